// Round 1
// baseline (145.691 us; speedup 1.0000x reference)
//
#include <hip/hip_runtime.h>
#include <math.h>

// LocalEnergyOpt R17 = R11 structure + group-2 direct-to-register loads.
// R11 ledger: ~39 us kernel = 92 MB mandatory line fetches; coalescing /
// byte-count / occupancy levers all falsified (R12-R15). R13's coalescing
// regression implies we are NOT fetch-rate-bound => attack the remaining
// structural serialization instead: the phase-B LDS round-trip.
// Change vs R11: rows >= 6000 (angle terms t>=1500, torsion terms t>=1200)
// are no longer staged regs->LDS->reread behind a second full-block
// barrier. The CONSUMING thread loads its own term's 4 (angle) / 5
// (torsion) dwords global->reg before group-1 compute (latency hides under
// it) and computes group-2 straight from registers + the coord LDS staged
// in phase A. Removes barrier-2, its vmcnt(0) drain, and a 144 KB/system
// LDS write+read round-trip. LDS shrinks 88464 -> 76464 B.
// Same-line fetch volume is provably unchanged (stride-36 4-B columns touch
// every 64-B line), so FETCH_SIZE should be flat; win is serialization only.

#define EBS 1024

constexpr int MAXLEN = 10000;
constexpr int NBT = 50, NAT = 100, NTT = 200;
constexpr float EPS = 1e-8f;

// LDS layout (bytes) — 76464 B
constexpr int OFF_SCF = 0;                     // 2000 atoms * float4 (x,y,z,-)
constexpr int OFF_SB  = OFF_SCF + 8000 * 4;    // 2000 * ushort4 bonds (i,j,ty,-)
constexpr int OFF_SA  = OFF_SB  + 8000 * 2;    // 6000 u16 angle rows (t<1500)
constexpr int OFF_ST4 = OFF_SA  + 6000 * 2;    // 1200 * ushort4 torsion ijkl
constexpr int OFF_STY = OFF_ST4 + 4800 * 2;    // 1200 u16 torsion type
constexpr int OFF_RBP = OFF_STY + 1200 * 2;    // 50*(k,r0)
constexpr int OFF_RAP = OFF_RBP + 100 * 4;     // 100*(k,th0)
constexpr int OFF_RTP = OFF_RAP + 200 * 4;     // 200*(k,cp,sp,n)
constexpr int OFF_SW  = OFF_RTP + 800 * 4;     // 16 f32 wave partials
constexpr int SMEM_BYTES = OFF_SW + 16 * 4;

__device__ __forceinline__ float acos_fast(float x) {
    // Abramowitz-Stegun 4.4.45, |err|<=6.8e-5 rad (absmax 0 across R9-R16)
    float t = fabsf(x);
    float p = fmaf(t, -0.0187293f, 0.0742610f);
    p = fmaf(p, t, -0.2121144f);
    p = fmaf(p, t, 1.5707288f);
    float r = sqrtf(1.0f - t) * p;
    return (x >= 0.0f) ? r : (3.14159265358979f - r);
}

__global__ __launch_bounds__(EBS) void energy_kernel(
    const float* __restrict__ features,   // [B, 10000, 9]
    const int*   __restrict__ lengths,    // [B, 9]
    const float* __restrict__ opt_pars,   // [350, 3]
    const float* __restrict__ bond_type,  // [50]
    const float* __restrict__ angle_type, // [100]
    const float* __restrict__ tor_type,   // [200]
    float*       __restrict__ out)        // [B]
{
    extern __shared__ __align__(16) char smem[];
    float*          scf = (float*)(smem + OFF_SCF);
    const float4*   sc4 = (const float4*)(smem + OFF_SCF);
    unsigned short* sb  = (unsigned short*)(smem + OFF_SB);
    const ushort4*  sb4 = (const ushort4*)(smem + OFF_SB);
    unsigned short* sa  = (unsigned short*)(smem + OFF_SA);
    const ushort4*  sa4 = (const ushort4*)(smem + OFF_SA);
    unsigned short* st4 = (unsigned short*)(smem + OFF_ST4);
    const ushort4*  st44= (const ushort4*)(smem + OFF_ST4);
    unsigned short* sty = (unsigned short*)(smem + OFF_STY);
    float*          rbp = (float*)(smem + OFF_RBP);
    float*          rap = (float*)(smem + OFF_RAP);
    float*          rtp = (float*)(smem + OFF_RTP);
    float*          sw  = (float*)(smem + OFF_SW);

    const int b   = blockIdx.x;
    const int tid = threadIdx.x;
    const float* __restrict__ fb = features + (size_t)b * MAXLEN * 9;

    // ---- resolved param tables ----
    if (tid < NBT) {
        int idx = (int)bond_type[tid];
        rbp[2*tid+0] = opt_pars[3*idx+0];
        rbp[2*tid+1] = opt_pars[3*idx+1];
    } else if (tid < NBT + NAT) {
        int i = tid - NBT;
        int idx = (int)angle_type[i];
        rap[2*i+0] = opt_pars[3*idx+0];
        rap[2*i+1] = opt_pars[3*idx+1];
    } else if (tid < NBT + NAT + NTT) {
        int i = tid - NBT - NAT;
        int idx = (int)tor_type[i];
        float p0 = opt_pars[3*idx+1];
        rtp[4*i+0] = opt_pars[3*idx+0];
        rtp[4*i+1] = cosf(p0);
        rtp[4*i+2] = sinf(p0);
        rtp[4*i+3] = opt_pars[3*idx+2];
    }

    // ---- Phase A: stage rows [0,6000) — coords(all) + bonds(all) +
    //      angle rows<6000 (t<1500) + torsion rows<6000 (t<1200) ----
    #pragma unroll
    for (int k = 0; k < 6; ++k) {
        const int i = tid + k * EBS;
        if (i < 6000) {
            const float* __restrict__ row = fb + 9 * i + 5;
            float vc = row[0];
            float vb = row[1];
            float va = row[2];
            float vt = row[3];
            const int q3 = i / 3, r3 = i - 3 * q3;      // atom / dim; bond t / slot
            scf[4 * q3 + r3] = vc;
            if (i < 5997) sb[4 * q3 + r3] = (unsigned short)(int)vb;
            sa[i] = (unsigned short)(int)va;            // i < 6000
            const int q5 = i / 5, r5 = i - 5 * q5;
            if (r5 < 4) st4[4 * q5 + r5] = (unsigned short)(int)vt;
            else        sty[q5]          = (unsigned short)(int)vt;
        }
    }
    __syncthreads();

    const int nb = lengths[b * 9 + 6] / 3;
    const int na = lengths[b * 9 + 7] / 4;
    const int nt = lengths[b * 9 + 8] / 5;

    // ---- term cores (coords from LDS, indices from caller) ----
    auto bond_core = [&](int qi, int qj, int ty) -> float {
        float4 pi = sc4[qi], pj = sc4[qj];
        float dx = pi.x - pj.x, dy = pi.y - pj.y, dz = pi.z - pj.z;
        float r  = sqrtf(dx*dx + dy*dy + dz*dz + EPS);
        float d  = r - rbp[2*ty+1];
        return rbp[2*ty+0] * d * d;
    };
    auto angle_core = [&](int qi, int qj, int qk, int ty) -> float {
        float4 pi = sc4[qi], pj = sc4[qj], pk = sc4[qk];
        float ux = pi.x - pj.x, uy = pi.y - pj.y, uz = pi.z - pj.z;
        float vx = pk.x - pj.x, vy = pk.y - pj.y, vz = pk.z - pj.z;
        float uv = ux*vx + uy*vy + uz*vz;
        float uu = ux*ux + uy*uy + uz*uz;
        float vv = vx*vx + vy*vy + vz*vz;
        float cth = uv * rsqrtf((uu + EPS) * (vv + EPS));
        cth = fminf(fmaxf(cth, -1.0f + 1e-6f), 1.0f - 1e-6f);
        float d = acos_fast(cth) - rap[2*ty+1];
        return rap[2*ty+0] * d * d;
    };
    auto tor_core = [&](int qi, int qj, int qk, int ql, int ty) -> float {
        float4 pi = sc4[qi], pj = sc4[qj], pk = sc4[qk], pl = sc4[ql];
        float b1x = pj.x - pi.x, b1y = pj.y - pi.y, b1z = pj.z - pi.z;
        float b2x = pk.x - pj.x, b2y = pk.y - pj.y, b2z = pk.z - pj.z;
        float b3x = pl.x - pk.x, b3y = pl.y - pk.y, b3z = pl.z - pk.z;
        float n1x = b1y*b2z - b1z*b2y;
        float n1y = b1z*b2x - b1x*b2z;
        float n1z = b1x*b2y - b1y*b2x;
        float n2x = b2y*b3z - b2z*b3y;
        float n2y = b2z*b3x - b2x*b3z;
        float n2z = b2x*b3y - b2y*b3x;
        float inv = rsqrtf(b2x*b2x + b2y*b2y + b2z*b2z + EPS);
        float hx = b2x * inv, hy = b2y * inv, hz = b2z * inv;
        float m1x = n1y*hz - n1z*hy;
        float m1y = n1z*hx - n1x*hz;
        float m1z = n1x*hy - n1y*hx;
        float sy = m1x*n2x + m1y*n2y + m1z*n2z;   // |n1||n2| sin(phi)
        float sx = n1x*n2x + n1y*n2y + n1z*n2z;   // |n1||n2| cos(phi)
        float rinv = rsqrtf(sx*sx + sy*sy + 1e-30f);
        float c1 = sx * rinv, s1 = sy * rinv;
        float c2 = fmaf(2.0f*c1, c1, -1.0f);
        float s2 = 2.0f * s1 * c1;
        float c3 = fmaf(2.0f*c1, c2, -c1);
        float s3 = fmaf(2.0f*c1, s2, -s1);
        float k  = rtp[4*ty+0];
        float cp = rtp[4*ty+1];
        float sp = rtp[4*ty+2];
        int   ni = (int)rtp[4*ty+3];
        float cn = (ni == 1) ? c1 : ((ni == 2) ? c2 : c3);
        float sn = (ni == 1) ? s1 : ((ni == 2) ? s2 : s3);
        return k * (1.0f + cn * cp + sn * sp);
    };

    float acc = 0.0f;

    // ---- group-2 direct loads (rows >= 6000) issued HERE so their latency
    //      hides under group-1 compute. Consuming thread loads its own
    //      term's rows straight to registers — no LDS demux, no barrier-2.
    const int ta = 1500 + tid;            // angle term for this thread
    const int tt = 1200 + tid;            // torsion term for this thread
    const bool hasA = (ta < na);
    const bool hasT = (tt < nt);
    float ga0 = 0.f, ga1 = 0.f, ga2 = 0.f, ga3 = 0.f;
    float gt0 = 0.f, gt1 = 0.f, gt2 = 0.f, gt3 = 0.f, gt4 = 0.f;
    if (hasA) {
        const float* __restrict__ ra = fb + 9 * (4 * ta) + 7;  // col 7
        ga0 = ra[0];  ga1 = ra[9];  ga2 = ra[18]; ga3 = ra[27];
    }
    if (hasT) {
        const float* __restrict__ rt = fb + 9 * (5 * tt) + 8;  // col 8
        gt0 = rt[0];  gt1 = rt[9];  gt2 = rt[18]; gt3 = rt[27]; gt4 = rt[36];
    }

    // ---- group-1 compute: bonds(all) + angles t<1500 + tors t<1200 ----
    {
        int t0 = tid, t1 = tid + EBS;              // independent -> ILP
        float e0 = 0.f, e1 = 0.f;
        if (t0 < nb) { ushort4 q = sb4[t0]; e0 = bond_core(q.x, q.y, q.z); }
        if (t1 < nb) { ushort4 q = sb4[t1]; e1 = bond_core(q.x, q.y, q.z); }
        acc += e0 + e1;
    }
    {
        const int lim = min(na, 1500);
        int t0 = tid, t1 = tid + EBS;
        float e0 = 0.f, e1 = 0.f;
        if (t0 < lim) { ushort4 q = sa4[t0]; e0 = angle_core(q.x, q.y, q.z, q.w); }
        if (t1 < lim) { ushort4 q = sa4[t1]; e1 = angle_core(q.x, q.y, q.z, q.w); }
        acc += e0 + e1;
    }
    {
        const int lim = min(nt, 1200);
        int t0 = tid, t1 = tid + EBS;
        float e0 = 0.f, e1 = 0.f;
        if (t0 < lim) { ushort4 q = st44[t0]; e0 = tor_core(q.x, q.y, q.z, q.w, sty[t0]); }
        if (t1 < lim) { ushort4 q = st44[t1]; e1 = tor_core(q.x, q.y, q.z, q.w, sty[t1]); }
        acc += e0 + e1;
    }

    // ---- group-2 compute: straight from registers + coord LDS ----
    if (hasA) acc += angle_core((int)ga0, (int)ga1, (int)ga2, (int)ga3);
    if (hasT) acc += tor_core((int)gt0, (int)gt1, (int)gt2, (int)gt3, (int)gt4);

    // ---- reduce: 64-lane shuffle, then cross-wave via LDS ----
    for (int off = 32; off > 0; off >>= 1)
        acc += __shfl_down(acc, off, 64);
    const int wave = tid >> 6, lane = tid & 63;
    if (lane == 0) sw[wave] = acc;
    __syncthreads();
    if (tid == 0) {
        float v = 0.0f;
        #pragma unroll
        for (int w = 0; w < EBS / 64; ++w) v += sw[w];
        out[b] = v;
    }
}

extern "C" void kernel_launch(void* const* d_in, const int* in_sizes, int n_in,
                              void* d_out, int out_size, void* d_ws, size_t ws_size,
                              hipStream_t stream) {
    const float* features   = (const float*)d_in[0];
    const int*   lengths    = (const int*)  d_in[1];
    const float* opt_pars   = (const float*)d_in[2];
    const float* bond_type  = (const float*)d_in[3];
    const float* angle_type = (const float*)d_in[4];
    const float* tor_type   = (const float*)d_in[5];
    float* out = (float*)d_out;

    // ~76.5 KB dynamic LDS (> 64 KB default); idempotent, capture-safe.
    hipFuncSetAttribute((const void*)energy_kernel,
                        hipFuncAttributeMaxDynamicSharedMemorySize, SMEM_BYTES);

    const int B = out_size;  // 256
    energy_kernel<<<B, EBS, SMEM_BYTES, stream>>>(
        features, lengths, opt_pars, bond_type, angle_type, tor_type, out);
}

// Round 2
// 144.251 us; speedup vs baseline: 1.0100x; 1.0100x over previous
//
#include <hip/hip_runtime.h>
#include <math.h>

// LocalEnergyOpt R18 == R16 == R11 (empirical best, 142.1-144.3 us bench,
// ~39 us kernel). Restored after R17 (group-2 direct-to-register loads)
// regressed to 145.7 us — the phase-B LDS round-trip is load-coalescing +
// collective latency-hiding, not overhead: per-term scattered 4-5-dword
// loads touch 64 lines/instruction at 4 B consumed each, vs row-linear
// phase-B loads that consume every fetched line densely.
// Falsified levers across sessions: fetch reduction, slicing, full
// coalescing+demux, register-demux, occupancy, serialization removal (R17).
// Ledger: ~39 us = ~92 MB mandatory line fetches (36-B rows -> every 64-B
// line contains live bytes; no byte-count lever exists) at the ~2.4-3.3
// TB/s effective rate this access mix sustains, plus dependent-gather
// tails. Remaining dur_us is harness re-poison fills (5x 360 MB @ 84%
// HBM peak), outside kernel control.
// Structure: fused, 1 block/system (grid 256), 1024 threads. Phase A stages
// rows [0,6000) (coords+bonds+78% of angle/torsion rows) via 4-dword window
// loads (row i -> floats 9i+5..9i+8); phase-B loads (rows >= 6000) are
// issued into registers BEFORE group-1 compute so their latency hides under
// it; regs->LDS; barrier; group-2. Compute: f4-padded coord LDS
// (ds_read_b128), manual 2x term unroll (ILP), trig-free torsions
// (Chebyshev + precomputed cos/sin p0), poly acos (absmax 0 since R9).

#define EBS 1024

constexpr int MAXLEN = 10000;
constexpr int NBT = 50, NAT = 100, NTT = 200;
constexpr float EPS = 1e-8f;

// LDS layout (bytes) — 88464 B -> 1 block/CU
constexpr int OFF_SCF = 0;                     // 2000 atoms * float4 (x,y,z,-)
constexpr int OFF_SB  = OFF_SCF + 8000 * 4;    // 2000 * ushort4 bonds (i,j,ty,-)
constexpr int OFF_SA  = OFF_SB  + 8000 * 2;    // 7992 u16 angles, natural 4/term
constexpr int OFF_ST4 = OFF_SA  + 8000 * 2;    // 2000 * ushort4 torsion ijkl
constexpr int OFF_STY = OFF_ST4 + 8000 * 2;    // 2000 u16 torsion type
constexpr int OFF_RBP = OFF_STY + 2000 * 2;    // 50*(k,r0)
constexpr int OFF_RAP = OFF_RBP + 100 * 4;     // 100*(k,th0)
constexpr int OFF_RTP = OFF_RAP + 200 * 4;     // 200*(k,cp,sp,n)
constexpr int OFF_SW  = OFF_RTP + 800 * 4;     // 16 f32 wave partials
constexpr int SMEM_BYTES = OFF_SW + 16 * 4;

__device__ __forceinline__ float acos_fast(float x) {
    // Abramowitz-Stegun 4.4.45, |err|<=6.8e-5 rad (absmax 0 across R9-R17)
    float t = fabsf(x);
    float p = fmaf(t, -0.0187293f, 0.0742610f);
    p = fmaf(p, t, -0.2121144f);
    p = fmaf(p, t, 1.5707288f);
    float r = sqrtf(1.0f - t) * p;
    return (x >= 0.0f) ? r : (3.14159265358979f - r);
}

__global__ __launch_bounds__(EBS) void energy_kernel(
    const float* __restrict__ features,   // [B, 10000, 9]
    const int*   __restrict__ lengths,    // [B, 9]
    const float* __restrict__ opt_pars,   // [350, 3]
    const float* __restrict__ bond_type,  // [50]
    const float* __restrict__ angle_type, // [100]
    const float* __restrict__ tor_type,   // [200]
    float*       __restrict__ out)        // [B]
{
    extern __shared__ __align__(16) char smem[];
    float*          scf = (float*)(smem + OFF_SCF);
    const float4*   sc4 = (const float4*)(smem + OFF_SCF);
    unsigned short* sb  = (unsigned short*)(smem + OFF_SB);
    const ushort4*  sb4 = (const ushort4*)(smem + OFF_SB);
    unsigned short* sa  = (unsigned short*)(smem + OFF_SA);
    const ushort4*  sa4 = (const ushort4*)(smem + OFF_SA);
    unsigned short* st4 = (unsigned short*)(smem + OFF_ST4);
    const ushort4*  st44= (const ushort4*)(smem + OFF_ST4);
    unsigned short* sty = (unsigned short*)(smem + OFF_STY);
    float*          rbp = (float*)(smem + OFF_RBP);
    float*          rap = (float*)(smem + OFF_RAP);
    float*          rtp = (float*)(smem + OFF_RTP);
    float*          sw  = (float*)(smem + OFF_SW);

    const int b   = blockIdx.x;
    const int tid = threadIdx.x;
    const float* __restrict__ fb = features + (size_t)b * MAXLEN * 9;

    // ---- resolved param tables ----
    if (tid < NBT) {
        int idx = (int)bond_type[tid];
        rbp[2*tid+0] = opt_pars[3*idx+0];
        rbp[2*tid+1] = opt_pars[3*idx+1];
    } else if (tid < NBT + NAT) {
        int i = tid - NBT;
        int idx = (int)angle_type[i];
        rap[2*i+0] = opt_pars[3*idx+0];
        rap[2*i+1] = opt_pars[3*idx+1];
    } else if (tid < NBT + NAT + NTT) {
        int i = tid - NBT - NAT;
        int idx = (int)tor_type[i];
        float p0 = opt_pars[3*idx+1];
        rtp[4*i+0] = opt_pars[3*idx+0];
        rtp[4*i+1] = cosf(p0);
        rtp[4*i+2] = sinf(p0);
        rtp[4*i+3] = opt_pars[3*idx+2];
    }

    // ---- Phase A: stage rows [0,6000) — coords(all) + bonds(all) +
    //      angle rows<6000 (t<1500) + torsion rows<6000 (t<1200) ----
    #pragma unroll
    for (int k = 0; k < 6; ++k) {
        const int i = tid + k * EBS;
        if (i < 6000) {
            const float* __restrict__ row = fb + 9 * i + 5;
            float vc = row[0];
            float vb = row[1];
            float va = row[2];
            float vt = row[3];
            const int q3 = i / 3, r3 = i - 3 * q3;      // atom / dim; bond t / slot
            scf[4 * q3 + r3] = vc;
            if (i < 5997) sb[4 * q3 + r3] = (unsigned short)(int)vb;
            sa[i] = (unsigned short)(int)va;            // i < 6000 < 7992
            const int q5 = i / 5, r5 = i - 5 * q5;
            if (r5 < 4) st4[4 * q5 + r5] = (unsigned short)(int)vt;
            else        sty[q5]          = (unsigned short)(int)vt;
        }
    }
    __syncthreads();

    const int nb = lengths[b * 9 + 6] / 3;
    const int na = lengths[b * 9 + 7] / 4;
    const int nt = lengths[b * 9 + 8] / 5;

    // ---- term bodies (read LDS only) ----
    auto bond_e = [&](int t) -> float {
        ushort4 q = sb4[t];
        float4 pi = sc4[q.x], pj = sc4[q.y];
        float dx = pi.x - pj.x, dy = pi.y - pj.y, dz = pi.z - pj.z;
        float r  = sqrtf(dx*dx + dy*dy + dz*dz + EPS);
        float d  = r - rbp[2*q.z+1];
        return rbp[2*q.z+0] * d * d;
    };
    auto angle_e = [&](int t) -> float {
        ushort4 q = sa4[t];
        float4 pi = sc4[q.x], pj = sc4[q.y], pk = sc4[q.z];
        float ux = pi.x - pj.x, uy = pi.y - pj.y, uz = pi.z - pj.z;
        float vx = pk.x - pj.x, vy = pk.y - pj.y, vz = pk.z - pj.z;
        float uv = ux*vx + uy*vy + uz*vz;
        float uu = ux*ux + uy*uy + uz*uz;
        float vv = vx*vx + vy*vy + vz*vz;
        float cth = uv * rsqrtf((uu + EPS) * (vv + EPS));
        cth = fminf(fmaxf(cth, -1.0f + 1e-6f), 1.0f - 1e-6f);
        float d = acos_fast(cth) - rap[2*q.w+1];
        return rap[2*q.w+0] * d * d;
    };
    auto tor_e = [&](int t) -> float {
        ushort4 q = st44[t];
        int ty = sty[t];
        float4 pi = sc4[q.x], pj = sc4[q.y], pk = sc4[q.z], pl = sc4[q.w];
        float b1x = pj.x - pi.x, b1y = pj.y - pi.y, b1z = pj.z - pi.z;
        float b2x = pk.x - pj.x, b2y = pk.y - pj.y, b2z = pk.z - pj.z;
        float b3x = pl.x - pk.x, b3y = pl.y - pk.y, b3z = pl.z - pk.z;
        float n1x = b1y*b2z - b1z*b2y;
        float n1y = b1z*b2x - b1x*b2z;
        float n1z = b1x*b2y - b1y*b2x;
        float n2x = b2y*b3z - b2z*b3y;
        float n2y = b2z*b3x - b2x*b3z;
        float n2z = b2x*b3y - b2y*b3x;
        float inv = rsqrtf(b2x*b2x + b2y*b2y + b2z*b2z + EPS);
        float hx = b2x * inv, hy = b2y * inv, hz = b2z * inv;
        float m1x = n1y*hz - n1z*hy;
        float m1y = n1z*hx - n1x*hz;
        float m1z = n1x*hy - n1y*hx;
        float sy = m1x*n2x + m1y*n2y + m1z*n2z;   // |n1||n2| sin(phi)
        float sx = n1x*n2x + n1y*n2y + n1z*n2z;   // |n1||n2| cos(phi)
        float rinv = rsqrtf(sx*sx + sy*sy + 1e-30f);
        float c1 = sx * rinv, s1 = sy * rinv;
        float c2 = fmaf(2.0f*c1, c1, -1.0f);
        float s2 = 2.0f * s1 * c1;
        float c3 = fmaf(2.0f*c1, c2, -c1);
        float s3 = fmaf(2.0f*c1, s2, -s1);
        float k  = rtp[4*ty+0];
        float cp = rtp[4*ty+1];
        float sp = rtp[4*ty+2];
        int   ni = (int)rtp[4*ty+3];
        float cn = (ni == 1) ? c1 : ((ni == 2) ? c2 : c3);
        float sn = (ni == 1) ? s1 : ((ni == 2) ? s2 : s3);
        return k * (1.0f + cn * cp + sn * sp);
    };

    float acc = 0.0f;

    // ---- Phase B loads (rows [6000,10000), cols 7+8) issued here so the
    //      compiler overlaps them with group-1 compute below ----
    float pva[4], pvt[4];
    #pragma unroll
    for (int k = 0; k < 4; ++k) {
        const int i = 6000 + tid + k * EBS;
        if (i < MAXLEN) {
            const float* __restrict__ row = fb + 9 * i + 7;
            pva[k] = row[0];
            pvt[k] = row[1];
        }
    }

    // ---- group-1 compute: bonds(all) + angles t<1500 + tors t<1200 ----
    {
        int t0 = tid, t1 = tid + EBS;              // independent -> ILP
        float e0 = (t0 < nb) ? bond_e(t0) : 0.0f;
        float e1 = (t1 < nb) ? bond_e(t1) : 0.0f;
        acc += e0 + e1;
    }
    {
        const int lim = min(na, 1500);
        int t0 = tid, t1 = tid + EBS;
        float e0 = (t0 < lim) ? angle_e(t0) : 0.0f;
        float e1 = (t1 < lim) ? angle_e(t1) : 0.0f;
        acc += e0 + e1;
    }
    {
        const int lim = min(nt, 1200);
        int t0 = tid, t1 = tid + EBS;
        float e0 = (t0 < lim) ? tor_e(t0) : 0.0f;
        float e1 = (t1 < lim) ? tor_e(t1) : 0.0f;
        acc += e0 + e1;
    }

    // ---- Phase B write-back regs -> LDS ----
    #pragma unroll
    for (int k = 0; k < 4; ++k) {
        const int i = 6000 + tid + k * EBS;
        if (i < MAXLEN) {
            if (i < 7992) sa[i] = (unsigned short)(int)pva[k];
            if (i < 9985) {
                const int q5 = i / 5, r5 = i - 5 * q5;
                if (r5 < 4) st4[4 * q5 + r5] = (unsigned short)(int)pvt[k];
                else        sty[q5]          = (unsigned short)(int)pvt[k];
            }
        }
    }
    __syncthreads();

    // ---- group-2 compute: angles t in [1500,na), tors t in [1200,nt) ----
    {
        int t = 1500 + tid;
        if (t < na) acc += angle_e(t);
        int u = 1200 + tid;
        if (u < nt) acc += tor_e(u);
    }

    // ---- reduce: 64-lane shuffle, then cross-wave via LDS ----
    for (int off = 32; off > 0; off >>= 1)
        acc += __shfl_down(acc, off, 64);
    const int wave = tid >> 6, lane = tid & 63;
    if (lane == 0) sw[wave] = acc;
    __syncthreads();
    if (tid == 0) {
        float v = 0.0f;
        #pragma unroll
        for (int w = 0; w < EBS / 64; ++w) v += sw[w];
        out[b] = v;
    }
}

extern "C" void kernel_launch(void* const* d_in, const int* in_sizes, int n_in,
                              void* d_out, int out_size, void* d_ws, size_t ws_size,
                              hipStream_t stream) {
    const float* features   = (const float*)d_in[0];
    const int*   lengths    = (const int*)  d_in[1];
    const float* opt_pars   = (const float*)d_in[2];
    const float* bond_type  = (const float*)d_in[3];
    const float* angle_type = (const float*)d_in[4];
    const float* tor_type   = (const float*)d_in[5];
    float* out = (float*)d_out;

    // ~86.4 KB dynamic LDS (> 64 KB default); idempotent, capture-safe.
    hipFuncSetAttribute((const void*)energy_kernel,
                        hipFuncAttributeMaxDynamicSharedMemorySize, SMEM_BYTES);

    const int B = out_size;  // 256
    energy_kernel<<<B, EBS, SMEM_BYTES, stream>>>(
        features, lengths, opt_pars, bond_type, angle_type, tor_type, out);
}